// Round 4
// baseline (235.528 us; speedup 1.0000x reference)
//
#include <hip/hip_runtime.h>

#define KDIM 768
#define HALF 3145728      // 4096*768 elements per x tensor
#define XAELEMS 6291456   // 8192*768
#define WELEMS 589824     // 768*768
#define QS 0.18033688f    // 0.125 * log2(e)

typedef __attribute__((ext_vector_type(8))) short short8;
typedef __attribute__((ext_vector_type(4))) short short4_;
typedef __attribute__((ext_vector_type(4))) float float4_;
typedef __attribute__((ext_vector_type(2))) unsigned int uint2_;

__device__ __forceinline__ unsigned short f2bf(float f) {
  unsigned int u = __float_as_uint(f);
  u += 0x7fffu + ((u >> 16) & 1u);   // RTN-even
  return (unsigned short)(u >> 16);
}

// pack two fp32 -> one u32 of two bf16 (round-half-up via +0x8000, then byte-perm)
__device__ __forceinline__ unsigned int pack2bf(float a, float b) {
  unsigned int ua = __float_as_uint(a) + 0x8000u;
  unsigned int ub = __float_as_uint(b) + 0x8000u;
  return __builtin_amdgcn_perm(ub, ua, 0x07060302);  // D = (bf(b)<<16)|bf(a)
}

__device__ __forceinline__ void gll16(const void* g, void* l) {
  __builtin_amdgcn_global_load_lds(
      (const __attribute__((address_space(1))) unsigned int*)g,
      (__attribute__((address_space(3))) unsigned int*)l, 16, 0, 0);
}

// ---------------- prep: fp32 -> bf16, plus blended-K inputs ----------------
__global__ void prep_x_kernel(const float* __restrict__ x1, const float* __restrict__ x2,
                              const float* __restrict__ cs,
                              unsigned short* __restrict__ xa, unsigned short* __restrict__ xb) {
  const int i = (blockIdx.x * 256 + threadIdx.x) * 4;
  const float s = cs[0], t_ = 1.0f - s;
  float4 a = *(const float4*)(x1 + i);
  float4 b = *(const float4*)(x2 + i);
  ushort4 ua = { f2bf(a.x), f2bf(a.y), f2bf(a.z), f2bf(a.w) };
  ushort4 ub = { f2bf(b.x), f2bf(b.y), f2bf(b.z), f2bf(b.w) };
  *(ushort4*)(xa + i) = ua;
  *(ushort4*)(xa + HALF + i) = ub;
  ushort4 c1 = { f2bf(t_*a.x + s*b.x), f2bf(t_*a.y + s*b.y), f2bf(t_*a.z + s*b.z), f2bf(t_*a.w + s*b.w) };
  ushort4 c2 = { f2bf(t_*b.x + s*a.x), f2bf(t_*b.y + s*a.y), f2bf(t_*b.z + s*a.z), f2bf(t_*b.w + s*a.w) };
  *(ushort4*)(xb + i) = c1;
  *(ushort4*)(xb + HALF + i) = c2;
}

__global__ void conv_w4_kernel(const float* __restrict__ w0, const float* __restrict__ w1,
                               const float* __restrict__ w2, const float* __restrict__ w3,
                               unsigned short* __restrict__ o0, unsigned short* __restrict__ o1,
                               unsigned short* __restrict__ o2, unsigned short* __restrict__ o3) {
  const int z = blockIdx.y;
  const float* w = (z == 0) ? w0 : (z == 1) ? w1 : (z == 2) ? w2 : w3;
  unsigned short* o = (z == 0) ? o0 : (z == 1) ? o1 : (z == 2) ? o2 : o3;
  const int i = (blockIdx.x * 256 + threadIdx.x) * 4;
  float4 a = *(const float4*)(w + i);
  ushort4 ua = { f2bf(a.x), f2bf(a.y), f2bf(a.z), f2bf(a.w) };
  *(ushort4*)(o + i) = ua;
}

// ---------------- shared GEMM mainloop (m97 structure) ----------------
__device__ __forceinline__ void gemm_mainloop(const unsigned short* __restrict__ A,
                                              const unsigned short* __restrict__ W,
                                              unsigned short* As, unsigned short* Bs,
                                              int m0, int n0, int t, float4_ (&acc)[4][4]) {
  const int lane = t & 63, quad = lane >> 4, lrow = lane & 15;
  const int wave = t >> 6;
  const int wm = (wave & 1) * 64, wn = (wave >> 1) * 64;
  for (int kt = 0; kt < KDIM; kt += 64) {
#pragma unroll
    for (int i = 0; i < 4; i++) {
      const int li = i * 256 + t;
      const int row = li >> 3, cc = (li & 7) * 8;
      gll16(A + (size_t)(m0 + row) * KDIM + kt + cc, As + li * 8);
      gll16(W + (size_t)(n0 + row) * KDIM + kt + cc, Bs + li * 8);
    }
    __syncthreads();
#pragma unroll
    for (int kk = 0; kk < 2; kk++) {
      short8 af[4], bfr[4];
#pragma unroll
      for (int i = 0; i < 4; i++)
        af[i] = *(const short8*)(As + (wm + i * 16 + lrow) * 64 + kk * 32 + quad * 8);
#pragma unroll
      for (int j = 0; j < 4; j++)
        bfr[j] = *(const short8*)(Bs + (wn + j * 16 + lrow) * 64 + kk * 32 + quad * 8);
#pragma unroll
      for (int i = 0; i < 4; i++)
#pragma unroll
        for (int j = 0; j < 4; j++)
          acc[i][j] = __builtin_amdgcn_mfma_f32_16x16x32_bf16(af[i], bfr[j], acc[i][j], 0, 0, 0);
    }
    __syncthreads();
  }
}

// ---------------- fused QKV projection (z = 0:Q, 1:K, 2:V) ----------------
__global__ __launch_bounds__(256, 2)
void qkv_gemm(const unsigned short* __restrict__ xa, const unsigned short* __restrict__ xb,
              const unsigned short* __restrict__ wq, const unsigned short* __restrict__ wk,
              const unsigned short* __restrict__ wv,
              const float* __restrict__ bq, const float* __restrict__ bk, const float* __restrict__ bv,
              unsigned short* __restrict__ qo, unsigned short* __restrict__ ko,
              unsigned short* __restrict__ vto) {
  __shared__ __align__(16) unsigned short smem[16384];   // As | Bs, reused as transpose buf
  unsigned short* As = smem;
  unsigned short* Bs = smem + 8192;
  const int t = threadIdx.x;
  const int z = blockIdx.z;
  const int m0 = blockIdx.x * 128, n0 = blockIdx.y * 128;
  const unsigned short* A = (z == 1) ? xb : xa;
  const unsigned short* W = (z == 0) ? wq : (z == 1) ? wk : wv;
  const float* bias = (z == 0) ? bq : (z == 1) ? bk : bv;
  float4_ acc[4][4];
#pragma unroll
  for (int i = 0; i < 4; i++)
#pragma unroll
    for (int j = 0; j < 4; j++) acc[i][j] = (float4_){0.f, 0.f, 0.f, 0.f};
  gemm_mainloop(A, W, As, Bs, m0, n0, t, acc);

  const int lane = t & 63, quad = lane >> 4, lrow = lane & 15;
  const int wave = t >> 6;
  const int wm = (wave & 1) * 64, wn = (wave >> 1) * 64;

  if (z == 2) {
    // per-wave transpose: Tb rows = n-local (d), cols = m-local (token), XOR-swizzled chunks
    unsigned short* Tb = smem + wave * 4096;
#pragma unroll
    for (int i = 0; i < 4; i++) {
#pragma unroll
      for (int j = 0; j < 4; j++) {
        const int nl = j * 16 + lrow;
        const float bn = bias[n0 + wn + nl];
#pragma unroll
        for (int r = 0; r < 4; r++) {
          const int ml = i * 16 + quad * 4 + r;
          const int c = ml >> 3;
          Tb[nl * 64 + ((c ^ (nl & 7)) * 8) + (ml & 7)] = f2bf(acc[i][j][r] + bn);
        }
      }
    }
    __asm__ __volatile__("s_waitcnt lgkmcnt(0)");
    const int sb = (m0 + wm) >> 11;
    const int hh = (n0 + wn) >> 6;
    const int tokbase = ((m0 + wm) & 2047);
    // Store V^T with tokens PERMUTED within each 64-group:
    //   pos(tau) = (tile>>1)*32 + quad4*8 + (tile&1)*4 + r   (tau = tile*16+quad4*4+r)
    // so attn's PV A-frag (k = quad*8+j, token pair map j<4 -> tile 2g, j>=4 -> 2g+1)
    // is ONE contiguous b128 in LDS at the same XOR pattern as the K reads.
    // Output chunk c' (8 tokens) = concat(Tb tokens tau_lo..+3, tau_lo+16..+19),
    // tau_lo = (c'>>2)*32 + (c'&3)*4.
#pragma unroll
    for (int i3 = 0; i3 < 8; i3++) {
      const int ci = i3 * 64 + lane;
      const int row = ci >> 3, cp_ = ci & 7;
      const int bl = (cp_ >> 2) * 4 + ((cp_ & 3) >> 1);   // tau_lo >> 3
      const int off = (cp_ & 1) * 4;                      // tau_lo & 7
      const int chlo = bl ^ (row & 7);
      const int chhi = (bl + 2) ^ (row & 7);
      short4_ lo = *(const short4_*)(Tb + row * 64 + chlo * 8 + off);
      short4_ hi = *(const short4_*)(Tb + row * 64 + chhi * 8 + off);
      short8 rd = __builtin_shufflevector(lo, hi, 0, 1, 2, 3, 4, 5, 6, 7);
      *(short8*)(vto + ((size_t)(sb * 12 + hh) * 64 + row) * 2048 + tokbase + cp_ * 8) = rd;
    }
  } else {
    unsigned short* dst = (z == 0) ? qo : ko;
    const float scale = (z == 0) ? QS : 1.0f;
#pragma unroll
    for (int i = 0; i < 4; i++) {
#pragma unroll
      for (int j = 0; j < 4; j++) {
        const int n = n0 + wn + j * 16 + lrow;
        const float bn = bias[n];
#pragma unroll
        for (int r = 0; r < 4; r++) {
          const int m = m0 + wm + i * 16 + quad * 4 + r;
          dst[(size_t)m * KDIM + n] = f2bf((acc[i][j][r] + bn) * scale);
        }
      }
    }
  }
}

// ---------------- output projection: fp32 epilogue into d_out ----------------
__global__ __launch_bounds__(256, 2)
void out_gemm(const unsigned short* __restrict__ ob, const unsigned short* __restrict__ wo,
              const float* __restrict__ bo, float* __restrict__ out) {
  __shared__ __align__(16) unsigned short As[128 * 64];
  __shared__ __align__(16) unsigned short Bs[128 * 64];
  const int t = threadIdx.x;
  const int m0 = blockIdx.x * 128, n0 = blockIdx.y * 128;
  float4_ acc[4][4];
#pragma unroll
  for (int i = 0; i < 4; i++)
#pragma unroll
    for (int j = 0; j < 4; j++) acc[i][j] = (float4_){0.f, 0.f, 0.f, 0.f};
  gemm_mainloop(ob, wo, As, Bs, m0, n0, t, acc);

  const int lane = t & 63, quad = lane >> 4, lrow = lane & 15;
  const int wave = t >> 6;
  const int wm = (wave & 1) * 64, wn = (wave >> 1) * 64;
#pragma unroll
  for (int i = 0; i < 4; i++) {
#pragma unroll
    for (int j = 0; j < 4; j++) {
      const int n = n0 + wn + j * 16 + lrow;
      const float bn = bo[n];
#pragma unroll
      for (int r = 0; r < 4; r++) {
        const int m = m0 + wm + i * 16 + quad * 4 + r;
        out[(size_t)m * KDIM + n] = acc[i][j][r] + bn;
      }
    }
  }
}

// ---------------- flash attention v6: interleaved MFMA/VALU compute ----------
// qg,kg: 8192x768 bf16 (q pre-scaled by SCALE*log2e); vt: (48,64,2048) bf16 TOKEN-PERMUTED
// (see qkv z==2); o: 8192x768 bf16. grid: 768 blocks; prob = bid%48, 16 q-tiles of 128.
// S^T = K*Q^T via 16x16x32 (nt-OUTER: each S^T tile's 4 MFMAs complete early so the
// exp2+pack of tile nt-1 schedules into tile nt's MFMA shadow). PV via 16x16x32 with
// adjacent S^T tile pairs fused along K; exppack(3) placed between PV(g0) and PV(g1)
// so it hides under PV(g0)'s MFMAs. l = fp32 VALU adds (no ones-MFMA: MFMA pipe is
// critical at ~620 cy/iter vs VALU ~360). 3-buffer counted-vmcnt staging pipeline.
__global__ __launch_bounds__(256, 2)
void attn_kernel(const unsigned short* __restrict__ qg, const unsigned short* __restrict__ kg,
                 const unsigned short* __restrict__ vt, unsigned short* __restrict__ o) {
  __shared__ __align__(16) unsigned short Ks[3][64 * 64];
  __shared__ __align__(16) unsigned short Vs[3][64 * 64];
  const int prob = blockIdx.x % 48;
  const int q0 = (blockIdx.x / 48) * 128;
  const int sb = prob / 12, h = prob % 12;
  const int t = threadIdx.x, w = t >> 6, lane = t & 63, quad = lane >> 4, lrow = lane & 15;
  const int mbase = sb * 2048;
  const size_t vbase = (size_t)prob * (64 * 2048);

  const float4_ z4 = (float4_){0.f, 0.f, 0.f, 0.f};

  // Q as B-operand frags (16x16x32): B[n=q=lrow][k=d=quad*8+j]
  short8 bq[2][2];
#pragma unroll
  for (int i = 0; i < 2; i++) {
    const unsigned short* qp = qg + (size_t)(mbase + q0 + w * 32 + i * 16 + lrow) * KDIM + h * 64 + quad * 8;
    bq[i][0] = *(const short8*)qp;
    bq[i][1] = *(const short8*)(qp + 32);
  }
  float l_part[2] = {0.f, 0.f};
  float4_ oa[2][4];   // O^T tiles [i][dt]: row d = dt*16+quad*4+r, col q = i*16+lrow
#pragma unroll
  for (int i = 0; i < 2; i++)
#pragma unroll
    for (int d = 0; d < 4; d++) oa[i][d] = (float4_){0.f, 0.f, 0.f, 0.f};

  auto stage = [&](int k0, int b) {
#pragma unroll
    for (int i2 = 0; i2 < 2; i2++) {
      const int li = i2 * 256 + t;
      const int row = li >> 3, p = li & 7;
      const int c = p ^ (row & 7);
      gll16(kg + (size_t)(mbase + k0 + row) * KDIM + h * 64 + c * 8, &Ks[b][li * 8]);
    }
#pragma unroll
    for (int i2 = 0; i2 < 2; i2++) {
      const int li = i2 * 256 + t;
      const int row = li >> 3, p = li & 7;
      const int c = p ^ (row & 7);
      gll16(vt + vbase + (size_t)row * 2048 + k0 + c * 8, &Vs[b][li * 8]);
    }
  };

  auto compute = [&](int b) {
    float4_ st[4][2];
    short4_ pb[2][4];

    // exp2 (no max-sub; |logit|<~8) + rounded pack + fp32 l-accumulate for tile p
    auto exppack = [&](int p) {
#pragma unroll
      for (int i = 0; i < 2; i++) {
        const float p0 = __builtin_amdgcn_exp2f(st[p][i][0]);
        const float p1 = __builtin_amdgcn_exp2f(st[p][i][1]);
        const float p2 = __builtin_amdgcn_exp2f(st[p][i][2]);
        const float p3 = __builtin_amdgcn_exp2f(st[p][i][3]);
        l_part[i] += (p0 + p1) + (p2 + p3);
        uint2_ uu = { pack2bf(p0, p1), pack2bf(p2, p3) };
        pb[i][p] = __builtin_bit_cast(short4_, uu);
      }
    };

    // S^T = K * Q^T, nt-outer: tile nt's MFMAs cover tile nt-1's exp/pack VALU
#pragma unroll
    for (int nt = 0; nt < 4; nt++) {
      const int rowb = (nt * 16 + lrow) * 64;
      short8 ak0 = *(const short8*)(&Ks[b][rowb + ((quad ^ (lrow & 7)) * 8)]);
      short8 ak1 = *(const short8*)(&Ks[b][rowb + (((4 + quad) ^ (lrow & 7)) * 8)]);
      st[nt][0] = __builtin_amdgcn_mfma_f32_16x16x32_bf16(ak0, bq[0][0], z4, 0, 0, 0);
      st[nt][1] = __builtin_amdgcn_mfma_f32_16x16x32_bf16(ak0, bq[1][0], z4, 0, 0, 0);
      st[nt][0] = __builtin_amdgcn_mfma_f32_16x16x32_bf16(ak1, bq[0][1], st[nt][0], 0, 0, 0);
      st[nt][1] = __builtin_amdgcn_mfma_f32_16x16x32_bf16(ak1, bq[1][1], st[nt][1], 0, 0, 0);
      if (nt >= 1) exppack(nt - 1);
    }

    // PV g=0 (needs pb[*][0..1]); exppack(3) between the clusters hides under g0 MFMAs
#pragma unroll
    for (int g = 0; g < 2; g++) {
      const short8 b80 = __builtin_shufflevector(pb[0][2 * g], pb[0][2 * g + 1], 0, 1, 2, 3, 4, 5, 6, 7);
      const short8 b81 = __builtin_shufflevector(pb[1][2 * g], pb[1][2 * g + 1], 0, 1, 2, 3, 4, 5, 6, 7);
#pragma unroll
      for (int dt = 0; dt < 4; dt++) {
        const int rb = (dt * 16 + lrow) * 64 + (((g * 4 + quad) ^ (lrow & 7)) * 8);
        short8 a8 = *(const short8*)(&Vs[b][rb]);
        oa[0][dt] = __builtin_amdgcn_mfma_f32_16x16x32_bf16(a8, b80, oa[0][dt], 0, 0, 0);
        oa[1][dt] = __builtin_amdgcn_mfma_f32_16x16x32_bf16(a8, b81, oa[1][dt], 0, 0, 0);
      }
      if (g == 0) exppack(3);
    }
  };

  stage(0, 0);
  stage(64, 1);

#define STEP(KT, CUR, STG)                                   \
  do {                                                       \
    asm volatile("s_waitcnt vmcnt(4)" ::: "memory");         \
    __builtin_amdgcn_s_barrier();                            \
    __builtin_amdgcn_sched_barrier(0);                       \
    stage(((KT) + 2) * 64, (STG));                           \
    compute(CUR);                                            \
  } while (0)

  for (int kt0 = 0; kt0 < 30; kt0 += 3) {
    STEP(kt0, 0, 2);
    STEP(kt0 + 1, 1, 0);
    STEP(kt0 + 2, 2, 1);
  }
  // kt = 30 (buf 0): stage(31) still in flight
  asm volatile("s_waitcnt vmcnt(4)" ::: "memory");
  __builtin_amdgcn_s_barrier();
  __builtin_amdgcn_sched_barrier(0);
  compute(0);
  // kt = 31 (buf 1): drain
  asm volatile("s_waitcnt vmcnt(0)" ::: "memory");
  __builtin_amdgcn_s_barrier();
  __builtin_amdgcn_sched_barrier(0);
  compute(1);
#undef STEP

  // epilogue: reduce l over quads, normalize, packed 8B stores
#pragma unroll
  for (int i = 0; i < 2; i++) {
    float l = l_part[i];
    l += __shfl_xor(l, 16);
    l += __shfl_xor(l, 32);
    const float inv = 1.0f / l;
    const size_t m = (size_t)mbase + q0 + w * 32 + i * 16 + lrow;
#pragma unroll
    for (int dt = 0; dt < 4; dt++) {
      uint2_ uu = { pack2bf(oa[i][dt][0] * inv, oa[i][dt][1] * inv),
                    pack2bf(oa[i][dt][2] * inv, oa[i][dt][3] * inv) };
      *(uint2_*)(o + m * KDIM + h * 64 + dt * 16 + quad * 4) = uu;
    }
  }
}

// ---------------- launch ----------------
extern "C" void kernel_launch(void* const* d_in, const int* in_sizes, int n_in,
                              void* d_out, int out_size, void* d_ws, size_t ws_size,
                              hipStream_t stream) {
  const float* x1 = (const float*)d_in[0];
  const float* x2 = (const float*)d_in[1];
  const float* Wq = (const float*)d_in[2];
  const float* bq = (const float*)d_in[3];
  const float* Wk = (const float*)d_in[4];
  const float* bk = (const float*)d_in[5];
  const float* Wv = (const float*)d_in[6];
  const float* bv = (const float*)d_in[7];
  const float* Wo = (const float*)d_in[8];
  const float* bo = (const float*)d_in[9];
  const float* cs = (const float*)d_in[10];
  float* out = (float*)d_out;

  char* ws = (char*)d_ws;
  size_t off = 0;
  auto alloc = [&](size_t bytes) {
    void* p = ws + off;
    off += (bytes + 255) & ~(size_t)255;
    return p;
  };
  unsigned short* xa  = (unsigned short*)alloc((size_t)XAELEMS * 2);
  unsigned short* xb  = (unsigned short*)alloc((size_t)XAELEMS * 2);
  unsigned short* wqb = (unsigned short*)alloc((size_t)WELEMS * 2);
  unsigned short* wkb = (unsigned short*)alloc((size_t)WELEMS * 2);
  unsigned short* wvb = (unsigned short*)alloc((size_t)WELEMS * 2);
  unsigned short* wob = (unsigned short*)alloc((size_t)WELEMS * 2);
  unsigned short* qg  = (unsigned short*)alloc((size_t)XAELEMS * 2);
  unsigned short* kgb = (unsigned short*)alloc((size_t)XAELEMS * 2);
  unsigned short* vtb = (unsigned short*)alloc((size_t)XAELEMS * 2);
  unsigned short* ob  = (unsigned short*)alloc((size_t)XAELEMS * 2);

  prep_x_kernel<<<HALF / 1024, 256, 0, stream>>>(x1, x2, cs, xa, xb);
  conv_w4_kernel<<<dim3(WELEMS / 1024, 4), 256, 0, stream>>>(Wq, Wk, Wv, Wo, wqb, wkb, wvb, wob);
  qkv_gemm<<<dim3(64, 6, 3), 256, 0, stream>>>(xa, xb, wqb, wkb, wvb, bq, bk, bv, qg, kgb, vtb);
  attn_kernel<<<48 * 16, 256, 0, stream>>>(qg, kgb, vtb, ob);
  out_gemm<<<dim3(64, 6), 256, 0, stream>>>(ob, wob, bo, out);
}

// Round 5
// 216.462 us; speedup vs baseline: 1.0881x; 1.0881x over previous
//
#include <hip/hip_runtime.h>

#define KDIM 768
#define HALF 3145728      // 4096*768 elements per x tensor
#define XAELEMS 6291456   // 8192*768
#define WELEMS 589824     // 768*768
#define QS 0.18033688f    // 0.125 * log2(e)

typedef __attribute__((ext_vector_type(8))) short short8;
typedef __attribute__((ext_vector_type(4))) short short4_;
typedef __attribute__((ext_vector_type(4))) float float4_;
typedef __attribute__((ext_vector_type(2))) unsigned int uint2_;

__device__ __forceinline__ unsigned short f2bf(float f) {
  unsigned int u = __float_as_uint(f);
  u += 0x7fffu + ((u >> 16) & 1u);   // RTN-even
  return (unsigned short)(u >> 16);
}

// pack two fp32 -> one u32 of two bf16 (round-half-up via +0x8000, then byte-perm)
__device__ __forceinline__ unsigned int pack2bf(float a, float b) {
  unsigned int ua = __float_as_uint(a) + 0x8000u;
  unsigned int ub = __float_as_uint(b) + 0x8000u;
  return __builtin_amdgcn_perm(ub, ua, 0x07060302);  // D = (bf(b)<<16)|bf(a)
}

// truncating pack (no rounding adds). Used for P: numerator (PV) and denominator
// (l via ones-MFMA) consume the SAME truncated values, so the bias cancels.
__device__ __forceinline__ unsigned int pack2bf_t(float a, float b) {
  return __builtin_amdgcn_perm(__float_as_uint(b), __float_as_uint(a), 0x07060302);
}

__device__ __forceinline__ void gll16(const void* g, void* l) {
  __builtin_amdgcn_global_load_lds(
      (const __attribute__((address_space(1))) unsigned int*)g,
      (__attribute__((address_space(3))) unsigned int*)l, 16, 0, 0);
}

// ---------------- prep: fp32 -> bf16, plus blended-K inputs ----------------
__global__ void prep_x_kernel(const float* __restrict__ x1, const float* __restrict__ x2,
                              const float* __restrict__ cs,
                              unsigned short* __restrict__ xa, unsigned short* __restrict__ xb) {
  const int i = (blockIdx.x * 256 + threadIdx.x) * 4;
  const float s = cs[0], t_ = 1.0f - s;
  float4 a = *(const float4*)(x1 + i);
  float4 b = *(const float4*)(x2 + i);
  ushort4 ua = { f2bf(a.x), f2bf(a.y), f2bf(a.z), f2bf(a.w) };
  ushort4 ub = { f2bf(b.x), f2bf(b.y), f2bf(b.z), f2bf(b.w) };
  *(ushort4*)(xa + i) = ua;
  *(ushort4*)(xa + HALF + i) = ub;
  ushort4 c1 = { f2bf(t_*a.x + s*b.x), f2bf(t_*a.y + s*b.y), f2bf(t_*a.z + s*b.z), f2bf(t_*a.w + s*b.w) };
  ushort4 c2 = { f2bf(t_*b.x + s*a.x), f2bf(t_*b.y + s*a.y), f2bf(t_*b.z + s*a.z), f2bf(t_*b.w + s*a.w) };
  *(ushort4*)(xb + i) = c1;
  *(ushort4*)(xb + HALF + i) = c2;
}

__global__ void conv_w4_kernel(const float* __restrict__ w0, const float* __restrict__ w1,
                               const float* __restrict__ w2, const float* __restrict__ w3,
                               unsigned short* __restrict__ o0, unsigned short* __restrict__ o1,
                               unsigned short* __restrict__ o2, unsigned short* __restrict__ o3) {
  const int z = blockIdx.y;
  const float* w = (z == 0) ? w0 : (z == 1) ? w1 : (z == 2) ? w2 : w3;
  unsigned short* o = (z == 0) ? o0 : (z == 1) ? o1 : (z == 2) ? o2 : o3;
  const int i = (blockIdx.x * 256 + threadIdx.x) * 4;
  float4 a = *(const float4*)(w + i);
  ushort4 ua = { f2bf(a.x), f2bf(a.y), f2bf(a.z), f2bf(a.w) };
  *(ushort4*)(o + i) = ua;
}

// ---------------- shared GEMM mainloop (m97 structure) ----------------
__device__ __forceinline__ void gemm_mainloop(const unsigned short* __restrict__ A,
                                              const unsigned short* __restrict__ W,
                                              unsigned short* As, unsigned short* Bs,
                                              int m0, int n0, int t, float4_ (&acc)[4][4]) {
  const int lane = t & 63, quad = lane >> 4, lrow = lane & 15;
  const int wave = t >> 6;
  const int wm = (wave & 1) * 64, wn = (wave >> 1) * 64;
  for (int kt = 0; kt < KDIM; kt += 64) {
#pragma unroll
    for (int i = 0; i < 4; i++) {
      const int li = i * 256 + t;
      const int row = li >> 3, cc = (li & 7) * 8;
      gll16(A + (size_t)(m0 + row) * KDIM + kt + cc, As + li * 8);
      gll16(W + (size_t)(n0 + row) * KDIM + kt + cc, Bs + li * 8);
    }
    __syncthreads();
#pragma unroll
    for (int kk = 0; kk < 2; kk++) {
      short8 af[4], bfr[4];
#pragma unroll
      for (int i = 0; i < 4; i++)
        af[i] = *(const short8*)(As + (wm + i * 16 + lrow) * 64 + kk * 32 + quad * 8);
#pragma unroll
      for (int j = 0; j < 4; j++)
        bfr[j] = *(const short8*)(Bs + (wn + j * 16 + lrow) * 64 + kk * 32 + quad * 8);
#pragma unroll
      for (int i = 0; i < 4; i++)
#pragma unroll
        for (int j = 0; j < 4; j++)
          acc[i][j] = __builtin_amdgcn_mfma_f32_16x16x32_bf16(af[i], bfr[j], acc[i][j], 0, 0, 0);
    }
    __syncthreads();
  }
}

// ---------------- fused QKV projection (z = 0:Q, 1:K, 2:V) ----------------
__global__ __launch_bounds__(256, 2)
void qkv_gemm(const unsigned short* __restrict__ xa, const unsigned short* __restrict__ xb,
              const unsigned short* __restrict__ wq, const unsigned short* __restrict__ wk,
              const unsigned short* __restrict__ wv,
              const float* __restrict__ bq, const float* __restrict__ bk, const float* __restrict__ bv,
              unsigned short* __restrict__ qo, unsigned short* __restrict__ ko,
              unsigned short* __restrict__ vto) {
  __shared__ __align__(16) unsigned short smem[16384];   // As | Bs, reused as transpose buf
  unsigned short* As = smem;
  unsigned short* Bs = smem + 8192;
  const int t = threadIdx.x;
  const int z = blockIdx.z;
  const int m0 = blockIdx.x * 128, n0 = blockIdx.y * 128;
  const unsigned short* A = (z == 1) ? xb : xa;
  const unsigned short* W = (z == 0) ? wq : (z == 1) ? wk : wv;
  const float* bias = (z == 0) ? bq : (z == 1) ? bk : bv;
  float4_ acc[4][4];
#pragma unroll
  for (int i = 0; i < 4; i++)
#pragma unroll
    for (int j = 0; j < 4; j++) acc[i][j] = (float4_){0.f, 0.f, 0.f, 0.f};
  gemm_mainloop(A, W, As, Bs, m0, n0, t, acc);

  const int lane = t & 63, quad = lane >> 4, lrow = lane & 15;
  const int wave = t >> 6;
  const int wm = (wave & 1) * 64, wn = (wave >> 1) * 64;

  if (z == 2) {
    // per-wave transpose: Tb rows = n-local (d), cols = m-local (token), XOR-swizzled chunks
    unsigned short* Tb = smem + wave * 4096;
#pragma unroll
    for (int i = 0; i < 4; i++) {
#pragma unroll
      for (int j = 0; j < 4; j++) {
        const int nl = j * 16 + lrow;
        const float bn = bias[n0 + wn + nl];
#pragma unroll
        for (int r = 0; r < 4; r++) {
          const int ml = i * 16 + quad * 4 + r;
          const int c = ml >> 3;
          Tb[nl * 64 + ((c ^ (nl & 7)) * 8) + (ml & 7)] = f2bf(acc[i][j][r] + bn);
        }
      }
    }
    __asm__ __volatile__("s_waitcnt lgkmcnt(0)");
    const int sb = (m0 + wm) >> 11;
    const int hh = (n0 + wn) >> 6;
    const int tokbase = ((m0 + wm) & 2047);
    // Store V^T with tokens PERMUTED within each 64-group:
    //   pos(tau) = (tile>>1)*32 + quad4*8 + (tile&1)*4 + r   (tau = tile*16+quad4*4+r)
    // so attn's PV A-frag (k = quad*8+j, token pair map j<4 -> tile 2g, j>=4 -> 2g+1)
    // is ONE contiguous b128 in LDS at the same XOR pattern as the K reads.
#pragma unroll
    for (int i3 = 0; i3 < 8; i3++) {
      const int ci = i3 * 64 + lane;
      const int row = ci >> 3, cp_ = ci & 7;
      const int bl = (cp_ >> 2) * 4 + ((cp_ & 3) >> 1);   // tau_lo >> 3
      const int off = (cp_ & 1) * 4;                      // tau_lo & 7
      const int chlo = bl ^ (row & 7);
      const int chhi = (bl + 2) ^ (row & 7);
      short4_ lo = *(const short4_*)(Tb + row * 64 + chlo * 8 + off);
      short4_ hi = *(const short4_*)(Tb + row * 64 + chhi * 8 + off);
      short8 rd = __builtin_shufflevector(lo, hi, 0, 1, 2, 3, 4, 5, 6, 7);
      *(short8*)(vto + ((size_t)(sb * 12 + hh) * 64 + row) * 2048 + tokbase + cp_ * 8) = rd;
    }
  } else {
    unsigned short* dst = (z == 0) ? qo : ko;
    const float scale = (z == 0) ? QS : 1.0f;
#pragma unroll
    for (int i = 0; i < 4; i++) {
#pragma unroll
      for (int j = 0; j < 4; j++) {
        const int n = n0 + wn + j * 16 + lrow;
        const float bn = bias[n];
#pragma unroll
        for (int r = 0; r < 4; r++) {
          const int m = m0 + wm + i * 16 + quad * 4 + r;
          dst[(size_t)m * KDIM + n] = f2bf((acc[i][j][r] + bn) * scale);
        }
      }
    }
  }
}

// ---------------- output projection: fp32 epilogue into d_out ----------------
__global__ __launch_bounds__(256, 2)
void out_gemm(const unsigned short* __restrict__ ob, const unsigned short* __restrict__ wo,
              const float* __restrict__ bo, float* __restrict__ out) {
  __shared__ __align__(16) unsigned short As[128 * 64];
  __shared__ __align__(16) unsigned short Bs[128 * 64];
  const int t = threadIdx.x;
  const int m0 = blockIdx.x * 128, n0 = blockIdx.y * 128;
  float4_ acc[4][4];
#pragma unroll
  for (int i = 0; i < 4; i++)
#pragma unroll
    for (int j = 0; j < 4; j++) acc[i][j] = (float4_){0.f, 0.f, 0.f, 0.f};
  gemm_mainloop(ob, wo, As, Bs, m0, n0, t, acc);

  const int lane = t & 63, quad = lane >> 4, lrow = lane & 15;
  const int wave = t >> 6;
  const int wm = (wave & 1) * 64, wn = (wave >> 1) * 64;
#pragma unroll
  for (int i = 0; i < 4; i++) {
#pragma unroll
    for (int j = 0; j < 4; j++) {
      const int n = n0 + wn + j * 16 + lrow;
      const float bn = bo[n];
#pragma unroll
      for (int r = 0; r < 4; r++) {
        const int m = m0 + wm + i * 16 + quad * 4 + r;
        out[(size_t)m * KDIM + n] = acc[i][j][r] + bn;
      }
    }
  }
}

// ---------------- flash attention v7: v5 (r3, 59us verified) + z4 C-in + setprio ----
// qg,kg: 8192x768 bf16 (q pre-scaled by SCALE*log2e); vt: (48,64,2048) bf16 TOKEN-PERMUTED
// (see qkv z==2); o: 8192x768 bf16. grid: 768 blocks; prob = bid%48, 16 q-tiles of 128.
// S^T = K*Q^T via 16x16x32 (kk-outer, unchanged from r3 except kk=0 uses z4 as C-in to
// kill 32 zero-init v_movs/iter); PV via 16x16x32, V^T A-frag = single b128 (token perm).
// l via ones-MFMA; truncating P pack (bias cancels in O/l). 3-buffer counted-vmcnt
// pipeline. s_setprio(1) wraps both MFMA clusters (T5, attn-positive in m191).
__global__ __launch_bounds__(256, 2)
void attn_kernel(const unsigned short* __restrict__ qg, const unsigned short* __restrict__ kg,
                 const unsigned short* __restrict__ vt, unsigned short* __restrict__ o) {
  __shared__ __align__(16) unsigned short Ks[3][64 * 64];
  __shared__ __align__(16) unsigned short Vs[3][64 * 64];
  const int prob = blockIdx.x % 48;
  const int q0 = (blockIdx.x / 48) * 128;
  const int sb = prob / 12, h = prob % 12;
  const int t = threadIdx.x, w = t >> 6, lane = t & 63, quad = lane >> 4, lrow = lane & 15;
  const int mbase = sb * 2048;
  const size_t vbase = (size_t)prob * (64 * 2048);

  const float4_ z4 = (float4_){0.f, 0.f, 0.f, 0.f};
  short8 ones8;
#pragma unroll
  for (int zz = 0; zz < 8; zz++) ones8[zz] = (short)0x3F80;   // bf16 1.0

  // Q as B-operand frags (16x16x32): B[n=q=lrow][k=d=quad*8+j]
  short8 bq[2][2];
#pragma unroll
  for (int i = 0; i < 2; i++) {
    const unsigned short* qp = qg + (size_t)(mbase + q0 + w * 32 + i * 16 + lrow) * KDIM + h * 64 + quad * 8;
    bq[i][0] = *(const short8*)qp;
    bq[i][1] = *(const short8*)(qp + 32);
  }
  float4_ la[2];   // l accumulators via ones-MFMA: la[i][*] = l[q=i*16+lrow] (rows identical)
  float4_ oa[2][4];   // O^T tiles [i][dt]: row d = dt*16+quad*4+r, col q = i*16+lrow
#pragma unroll
  for (int i = 0; i < 2; i++) {
    la[i] = (float4_){0.f, 0.f, 0.f, 0.f};
#pragma unroll
    for (int d = 0; d < 4; d++) oa[i][d] = (float4_){0.f, 0.f, 0.f, 0.f};
  }

  auto stage = [&](int k0, int b) {
#pragma unroll
    for (int i2 = 0; i2 < 2; i2++) {
      const int li = i2 * 256 + t;
      const int row = li >> 3, p = li & 7;
      const int c = p ^ (row & 7);
      gll16(kg + (size_t)(mbase + k0 + row) * KDIM + h * 64 + c * 8, &Ks[b][li * 8]);
    }
#pragma unroll
    for (int i2 = 0; i2 < 2; i2++) {
      const int li = i2 * 256 + t;
      const int row = li >> 3, p = li & 7;
      const int c = p ^ (row & 7);
      gll16(vt + vbase + (size_t)row * 2048 + k0 + c * 8, &Vs[b][li * 8]);
    }
  };

  auto compute = [&](int b) {
    // S^T = K * Q^T (log2-scaled via Q), kk-outer exactly as r3; kk=0 takes z4 as C-in
    float4_ st[4][2];
    __builtin_amdgcn_s_setprio(1);
#pragma unroll
    for (int nt = 0; nt < 4; nt++) {
      short8 ak = *(const short8*)(&Ks[b][(nt * 16 + lrow) * 64 + ((quad ^ (lrow & 7)) * 8)]);
      st[nt][0] = __builtin_amdgcn_mfma_f32_16x16x32_bf16(ak, bq[0][0], z4, 0, 0, 0);
      st[nt][1] = __builtin_amdgcn_mfma_f32_16x16x32_bf16(ak, bq[1][0], z4, 0, 0, 0);
    }
#pragma unroll
    for (int nt = 0; nt < 4; nt++) {
      short8 ak = *(const short8*)(&Ks[b][(nt * 16 + lrow) * 64 + (((4 + quad) ^ (lrow & 7)) * 8)]);
      st[nt][0] = __builtin_amdgcn_mfma_f32_16x16x32_bf16(ak, bq[0][1], st[nt][0], 0, 0, 0);
      st[nt][1] = __builtin_amdgcn_mfma_f32_16x16x32_bf16(ak, bq[1][1], st[nt][1], 0, 0, 0);
    }
    __builtin_amdgcn_s_setprio(0);

    // exp2 (no max-sub; |logit|<~8), truncate-pack pairs -> PV B-frags in registers
    short4_ pb[2][4];
#pragma unroll
    for (int nt = 0; nt < 4; nt++)
#pragma unroll
      for (int i = 0; i < 2; i++) {
        const float p0 = __builtin_amdgcn_exp2f(st[nt][i][0]);
        const float p1 = __builtin_amdgcn_exp2f(st[nt][i][1]);
        const float p2 = __builtin_amdgcn_exp2f(st[nt][i][2]);
        const float p3 = __builtin_amdgcn_exp2f(st[nt][i][3]);
        uint2_ uu = { pack2bf_t(p0, p1), pack2bf_t(p2, p3) };
        pb[i][nt] = __builtin_bit_cast(short4_, uu);
      }

    // O^T += V^T * P and l += 1^T * P : 16x16x32, st tile pairs (2g,2g+1) fused along K
    __builtin_amdgcn_s_setprio(1);
#pragma unroll
    for (int g = 0; g < 2; g++) {
      const short8 b80 = __builtin_shufflevector(pb[0][2 * g], pb[0][2 * g + 1], 0, 1, 2, 3, 4, 5, 6, 7);
      const short8 b81 = __builtin_shufflevector(pb[1][2 * g], pb[1][2 * g + 1], 0, 1, 2, 3, 4, 5, 6, 7);
      la[0] = __builtin_amdgcn_mfma_f32_16x16x32_bf16(ones8, b80, la[0], 0, 0, 0);
      la[1] = __builtin_amdgcn_mfma_f32_16x16x32_bf16(ones8, b81, la[1], 0, 0, 0);
#pragma unroll
      for (int dt = 0; dt < 4; dt++) {
        const int rb = (dt * 16 + lrow) * 64 + (((g * 4 + quad) ^ (lrow & 7)) * 8);
        short8 a8 = *(const short8*)(&Vs[b][rb]);
        oa[0][dt] = __builtin_amdgcn_mfma_f32_16x16x32_bf16(a8, b80, oa[0][dt], 0, 0, 0);
        oa[1][dt] = __builtin_amdgcn_mfma_f32_16x16x32_bf16(a8, b81, oa[1][dt], 0, 0, 0);
      }
    }
    __builtin_amdgcn_s_setprio(0);
  };

  stage(0, 0);
  stage(64, 1);

#define STEP(KT, CUR, STG)                                   \
  do {                                                       \
    asm volatile("s_waitcnt vmcnt(4)" ::: "memory");         \
    __builtin_amdgcn_s_barrier();                            \
    __builtin_amdgcn_sched_barrier(0);                       \
    stage(((KT) + 2) * 64, (STG));                           \
    compute(CUR);                                            \
  } while (0)

  for (int kt0 = 0; kt0 < 30; kt0 += 3) {
    STEP(kt0, 0, 2);
    STEP(kt0 + 1, 1, 0);
    STEP(kt0 + 2, 2, 1);
  }
  // kt = 30 (buf 0): stage(31) still in flight
  asm volatile("s_waitcnt vmcnt(4)" ::: "memory");
  __builtin_amdgcn_s_barrier();
  __builtin_amdgcn_sched_barrier(0);
  compute(0);
  // kt = 31 (buf 1): drain
  asm volatile("s_waitcnt vmcnt(0)" ::: "memory");
  __builtin_amdgcn_s_barrier();
  __builtin_amdgcn_sched_barrier(0);
  compute(1);
#undef STEP

  // epilogue: l already reduced per-lane by ones-MFMA; normalize, packed 8B stores
#pragma unroll
  for (int i = 0; i < 2; i++) {
    const float inv = 1.0f / la[i][0];
    const size_t m = (size_t)mbase + q0 + w * 32 + i * 16 + lrow;
#pragma unroll
    for (int dt = 0; dt < 4; dt++) {
      uint2_ uu = { pack2bf(oa[i][dt][0] * inv, oa[i][dt][1] * inv),
                    pack2bf(oa[i][dt][2] * inv, oa[i][dt][3] * inv) };
      *(uint2_*)(o + m * KDIM + h * 64 + dt * 16 + quad * 4) = uu;
    }
  }
}

// ---------------- launch ----------------
extern "C" void kernel_launch(void* const* d_in, const int* in_sizes, int n_in,
                              void* d_out, int out_size, void* d_ws, size_t ws_size,
                              hipStream_t stream) {
  const float* x1 = (const float*)d_in[0];
  const float* x2 = (const float*)d_in[1];
  const float* Wq = (const float*)d_in[2];
  const float* bq = (const float*)d_in[3];
  const float* Wk = (const float*)d_in[4];
  const float* bk = (const float*)d_in[5];
  const float* Wv = (const float*)d_in[6];
  const float* bv = (const float*)d_in[7];
  const float* Wo = (const float*)d_in[8];
  const float* bo = (const float*)d_in[9];
  const float* cs = (const float*)d_in[10];
  float* out = (float*)d_out;

  char* ws = (char*)d_ws;
  size_t off = 0;
  auto alloc = [&](size_t bytes) {
    void* p = ws + off;
    off += (bytes + 255) & ~(size_t)255;
    return p;
  };
  unsigned short* xa  = (unsigned short*)alloc((size_t)XAELEMS * 2);
  unsigned short* xb  = (unsigned short*)alloc((size_t)XAELEMS * 2);
  unsigned short* wqb = (unsigned short*)alloc((size_t)WELEMS * 2);
  unsigned short* wkb = (unsigned short*)alloc((size_t)WELEMS * 2);
  unsigned short* wvb = (unsigned short*)alloc((size_t)WELEMS * 2);
  unsigned short* wob = (unsigned short*)alloc((size_t)WELEMS * 2);
  unsigned short* qg  = (unsigned short*)alloc((size_t)XAELEMS * 2);
  unsigned short* kgb = (unsigned short*)alloc((size_t)XAELEMS * 2);
  unsigned short* vtb = (unsigned short*)alloc((size_t)XAELEMS * 2);
  unsigned short* ob  = (unsigned short*)alloc((size_t)XAELEMS * 2);

  prep_x_kernel<<<HALF / 1024, 256, 0, stream>>>(x1, x2, cs, xa, xb);
  conv_w4_kernel<<<dim3(WELEMS / 1024, 4), 256, 0, stream>>>(Wq, Wk, Wv, Wo, wqb, wkb, wvb, wob);
  qkv_gemm<<<dim3(64, 6, 3), 256, 0, stream>>>(xa, xb, wqb, wkb, wvb, bq, bk, bv, qg, kgb, vtb);
  attn_kernel<<<48 * 16, 256, 0, stream>>>(qg, kgb, vtb, ob);
  out_gemm<<<dim3(64, 6), 256, 0, stream>>>(ob, wob, bo, out);
}

// Round 6
// 200.475 us; speedup vs baseline: 1.1748x; 1.0797x over previous
//
#include <hip/hip_runtime.h>

#define KDIM 768
#define HALF 3145728      // 4096*768 elements per x tensor
#define XAELEMS 6291456   // 8192*768
#define WELEMS 589824     // 768*768
#define QS 0.18033688f    // 0.125 * log2(e)

typedef __attribute__((ext_vector_type(8))) short short8;
typedef __attribute__((ext_vector_type(4))) short short4_;
typedef __attribute__((ext_vector_type(4))) float float4_;
typedef __attribute__((ext_vector_type(2))) unsigned int uint2_;

__device__ __forceinline__ unsigned short f2bf(float f) {
  unsigned int u = __float_as_uint(f);
  u += 0x7fffu + ((u >> 16) & 1u);   // RTN-even
  return (unsigned short)(u >> 16);
}

// pack two fp32 -> one u32 of two bf16 (round-half-up via +0x8000, then byte-perm)
__device__ __forceinline__ unsigned int pack2bf(float a, float b) {
  unsigned int ua = __float_as_uint(a) + 0x8000u;
  unsigned int ub = __float_as_uint(b) + 0x8000u;
  return __builtin_amdgcn_perm(ub, ua, 0x07060302);  // D = (bf(b)<<16)|bf(a)
}

// truncating pack (no rounding adds). Used for P: numerator (PV) and denominator
// (l via ones-MFMA) consume the SAME truncated values, so the bias cancels.
__device__ __forceinline__ unsigned int pack2bf_t(float a, float b) {
  return __builtin_amdgcn_perm(__float_as_uint(b), __float_as_uint(a), 0x07060302);
}

__device__ __forceinline__ void gll16(const void* g, void* l) {
  __builtin_amdgcn_global_load_lds(
      (const __attribute__((address_space(1))) unsigned int*)g,
      (__attribute__((address_space(3))) unsigned int*)l, 16, 0, 0);
}

// ---------------- prep: fp32 -> bf16, plus blended-K inputs ----------------
__global__ void prep_x_kernel(const float* __restrict__ x1, const float* __restrict__ x2,
                              const float* __restrict__ cs,
                              unsigned short* __restrict__ xa, unsigned short* __restrict__ xb) {
  const int i = (blockIdx.x * 256 + threadIdx.x) * 4;
  const float s = cs[0], t_ = 1.0f - s;
  float4 a = *(const float4*)(x1 + i);
  float4 b = *(const float4*)(x2 + i);
  ushort4 ua = { f2bf(a.x), f2bf(a.y), f2bf(a.z), f2bf(a.w) };
  ushort4 ub = { f2bf(b.x), f2bf(b.y), f2bf(b.z), f2bf(b.w) };
  *(ushort4*)(xa + i) = ua;
  *(ushort4*)(xa + HALF + i) = ub;
  ushort4 c1 = { f2bf(t_*a.x + s*b.x), f2bf(t_*a.y + s*b.y), f2bf(t_*a.z + s*b.z), f2bf(t_*a.w + s*b.w) };
  ushort4 c2 = { f2bf(t_*b.x + s*a.x), f2bf(t_*b.y + s*a.y), f2bf(t_*b.z + s*a.z), f2bf(t_*b.w + s*a.w) };
  *(ushort4*)(xb + i) = c1;
  *(ushort4*)(xb + HALF + i) = c2;
}

__global__ void conv_w4_kernel(const float* __restrict__ w0, const float* __restrict__ w1,
                               const float* __restrict__ w2, const float* __restrict__ w3,
                               unsigned short* __restrict__ o0, unsigned short* __restrict__ o1,
                               unsigned short* __restrict__ o2, unsigned short* __restrict__ o3) {
  const int z = blockIdx.y;
  const float* w = (z == 0) ? w0 : (z == 1) ? w1 : (z == 2) ? w2 : w3;
  unsigned short* o = (z == 0) ? o0 : (z == 1) ? o1 : (z == 2) ? o2 : o3;
  const int i = (blockIdx.x * 256 + threadIdx.x) * 4;
  float4 a = *(const float4*)(w + i);
  ushort4 ua = { f2bf(a.x), f2bf(a.y), f2bf(a.z), f2bf(a.w) };
  *(ushort4*)(o + i) = ua;
}

// ---------------- shared GEMM mainloop: dbuf + XOR-swizzle + single barrier ----
// T3-minimum pipeline (attn-proven): prologue stage(0); per K-step
// {vmcnt(0); s_barrier; stage(kt+1, b^1); ds_read+MFMA on buf b}. stage(kt+1)'s
// 8 loads land during compute(kt) (~620 MFMA cycles of cover) instead of being
// drained immediately. LDS: As/Bs double-buffered = 64 KB -> 2 blocks/CU.
// Bank conflicts: linear [128][64] rows are 128B apart => 16-way conflict on
// ds_read_b128 (m98: 1.7e7). Fix per rule #21: inverse-XOR the GLOBAL source
// chunk (c = p ^ (row&7)) so LDS is chunk-swizzled, read with the same XOR.
// Trailing barrier protects epilogue smem reuse (qkv z==2 transpose buffer).
__device__ __forceinline__ void gemm_mainloop(const unsigned short* __restrict__ A,
                                              const unsigned short* __restrict__ W,
                                              unsigned short* As, unsigned short* Bs,
                                              int m0, int n0, int t, float4_ (&acc)[4][4]) {
  const int lane = t & 63, quad = lane >> 4, lrow = lane & 15;
  const int wave = t >> 6;
  const int wm = (wave & 1) * 64, wn = (wave >> 1) * 64;

  auto stg = [&](int kt, int b) {
#pragma unroll
    for (int i = 0; i < 4; i++) {
      const int li = i * 256 + t;
      const int row = li >> 3, p = li & 7;
      const int c = (p ^ (row & 7)) * 8;
      gll16(A + (size_t)(m0 + row) * KDIM + kt + c, As + b * 8192 + li * 8);
      gll16(W + (size_t)(n0 + row) * KDIM + kt + c, Bs + b * 8192 + li * 8);
    }
  };

  stg(0, 0);
  const int NT = KDIM / 64;   // 12
  for (int kt = 0; kt < NT; kt++) {
    const int b = kt & 1;
    asm volatile("s_waitcnt vmcnt(0)" ::: "memory");
    __builtin_amdgcn_s_barrier();
    __builtin_amdgcn_sched_barrier(0);
    if (kt + 1 < NT) stg((kt + 1) * 64, b ^ 1);
#pragma unroll
    for (int kk = 0; kk < 2; kk++) {
      short8 af[4], bfr[4];
#pragma unroll
      for (int i = 0; i < 4; i++)
        af[i] = *(const short8*)(As + b * 8192 + (wm + i * 16 + lrow) * 64 +
                                 (((kk * 4 + quad) ^ (lrow & 7)) * 8));
#pragma unroll
      for (int j = 0; j < 4; j++)
        bfr[j] = *(const short8*)(Bs + b * 8192 + (wn + j * 16 + lrow) * 64 +
                                  (((kk * 4 + quad) ^ (lrow & 7)) * 8));
#pragma unroll
      for (int i = 0; i < 4; i++)
#pragma unroll
        for (int j = 0; j < 4; j++)
          acc[i][j] = __builtin_amdgcn_mfma_f32_16x16x32_bf16(af[i], bfr[j], acc[i][j], 0, 0, 0);
    }
  }
  __syncthreads();   // all LDS reads retired before epilogue reuses smem
}

// ---------------- fused QKV projection (z = 0:Q, 1:K, 2:V) ----------------
__global__ __launch_bounds__(256, 2)
void qkv_gemm(const unsigned short* __restrict__ xa, const unsigned short* __restrict__ xb,
              const unsigned short* __restrict__ wq, const unsigned short* __restrict__ wk,
              const unsigned short* __restrict__ wv,
              const float* __restrict__ bq, const float* __restrict__ bk, const float* __restrict__ bv,
              unsigned short* __restrict__ qo, unsigned short* __restrict__ ko,
              unsigned short* __restrict__ vto) {
  __shared__ __align__(16) unsigned short smem[32768];   // As dbuf | Bs dbuf; reused as transpose buf
  unsigned short* As = smem;
  unsigned short* Bs = smem + 16384;
  const int t = threadIdx.x;
  const int z = blockIdx.z;
  const int m0 = blockIdx.x * 128, n0 = blockIdx.y * 128;
  const unsigned short* A = (z == 1) ? xb : xa;
  const unsigned short* W = (z == 0) ? wq : (z == 1) ? wk : wv;
  const float* bias = (z == 0) ? bq : (z == 1) ? bk : bv;
  float4_ acc[4][4];
#pragma unroll
  for (int i = 0; i < 4; i++)
#pragma unroll
    for (int j = 0; j < 4; j++) acc[i][j] = (float4_){0.f, 0.f, 0.f, 0.f};
  gemm_mainloop(A, W, As, Bs, m0, n0, t, acc);

  const int lane = t & 63, quad = lane >> 4, lrow = lane & 15;
  const int wave = t >> 6;
  const int wm = (wave & 1) * 64, wn = (wave >> 1) * 64;

  if (z == 2) {
    // per-wave transpose: Tb rows = n-local (d), cols = m-local (token), XOR-swizzled chunks
    // (wave slices live in [0,16384) = As region; mainloop's trailing barrier protects it)
    unsigned short* Tb = smem + wave * 4096;
#pragma unroll
    for (int i = 0; i < 4; i++) {
#pragma unroll
      for (int j = 0; j < 4; j++) {
        const int nl = j * 16 + lrow;
        const float bn = bias[n0 + wn + nl];
#pragma unroll
        for (int r = 0; r < 4; r++) {
          const int ml = i * 16 + quad * 4 + r;
          const int c = ml >> 3;
          Tb[nl * 64 + ((c ^ (nl & 7)) * 8) + (ml & 7)] = f2bf(acc[i][j][r] + bn);
        }
      }
    }
    __asm__ __volatile__("s_waitcnt lgkmcnt(0)");
    const int sb = (m0 + wm) >> 11;
    const int hh = (n0 + wn) >> 6;
    const int tokbase = ((m0 + wm) & 2047);
    // Store V^T with tokens PERMUTED within each 64-group:
    //   pos(tau) = (tile>>1)*32 + quad4*8 + (tile&1)*4 + r   (tau = tile*16+quad4*4+r)
    // so attn's PV A-frag (k = quad*8+j, token pair map j<4 -> tile 2g, j>=4 -> 2g+1)
    // is ONE contiguous b128 in LDS at the same XOR pattern as the K reads.
#pragma unroll
    for (int i3 = 0; i3 < 8; i3++) {
      const int ci = i3 * 64 + lane;
      const int row = ci >> 3, cp_ = ci & 7;
      const int bl = (cp_ >> 2) * 4 + ((cp_ & 3) >> 1);   // tau_lo >> 3
      const int off = (cp_ & 1) * 4;                      // tau_lo & 7
      const int chlo = bl ^ (row & 7);
      const int chhi = (bl + 2) ^ (row & 7);
      short4_ lo = *(const short4_*)(Tb + row * 64 + chlo * 8 + off);
      short4_ hi = *(const short4_*)(Tb + row * 64 + chhi * 8 + off);
      short8 rd = __builtin_shufflevector(lo, hi, 0, 1, 2, 3, 4, 5, 6, 7);
      *(short8*)(vto + ((size_t)(sb * 12 + hh) * 64 + row) * 2048 + tokbase + cp_ * 8) = rd;
    }
  } else {
    unsigned short* dst = (z == 0) ? qo : ko;
    const float scale = (z == 0) ? QS : 1.0f;
#pragma unroll
    for (int i = 0; i < 4; i++) {
#pragma unroll
      for (int j = 0; j < 4; j++) {
        const int n = n0 + wn + j * 16 + lrow;
        const float bn = bias[n];
#pragma unroll
        for (int r = 0; r < 4; r++) {
          const int m = m0 + wm + i * 16 + quad * 4 + r;
          dst[(size_t)m * KDIM + n] = f2bf((acc[i][j][r] + bn) * scale);
        }
      }
    }
  }
}

// ---------------- output projection: fp32 epilogue into d_out ----------------
__global__ __launch_bounds__(256, 2)
void out_gemm(const unsigned short* __restrict__ ob, const unsigned short* __restrict__ wo,
              const float* __restrict__ bo, float* __restrict__ out) {
  __shared__ __align__(16) unsigned short smem[32768];   // As dbuf | Bs dbuf
  unsigned short* As = smem;
  unsigned short* Bs = smem + 16384;
  const int t = threadIdx.x;
  const int m0 = blockIdx.x * 128, n0 = blockIdx.y * 128;
  float4_ acc[4][4];
#pragma unroll
  for (int i = 0; i < 4; i++)
#pragma unroll
    for (int j = 0; j < 4; j++) acc[i][j] = (float4_){0.f, 0.f, 0.f, 0.f};
  gemm_mainloop(ob, wo, As, Bs, m0, n0, t, acc);

  const int lane = t & 63, quad = lane >> 4, lrow = lane & 15;
  const int wave = t >> 6;
  const int wm = (wave & 1) * 64, wn = (wave >> 1) * 64;
#pragma unroll
  for (int i = 0; i < 4; i++) {
#pragma unroll
    for (int j = 0; j < 4; j++) {
      const int n = n0 + wn + j * 16 + lrow;
      const float bn = bo[n];
#pragma unroll
      for (int r = 0; r < 4; r++) {
        const int m = m0 + wm + i * 16 + quad * 4 + r;
        out[(size_t)m * KDIM + n] = acc[i][j][r] + bn;
      }
    }
  }
}

// ---------------- flash attention v7 (r5-verified, 56.5us): unchanged ----------
__global__ __launch_bounds__(256, 2)
void attn_kernel(const unsigned short* __restrict__ qg, const unsigned short* __restrict__ kg,
                 const unsigned short* __restrict__ vt, unsigned short* __restrict__ o) {
  __shared__ __align__(16) unsigned short Ks[3][64 * 64];
  __shared__ __align__(16) unsigned short Vs[3][64 * 64];
  const int prob = blockIdx.x % 48;
  const int q0 = (blockIdx.x / 48) * 128;
  const int sb = prob / 12, h = prob % 12;
  const int t = threadIdx.x, w = t >> 6, lane = t & 63, quad = lane >> 4, lrow = lane & 15;
  const int mbase = sb * 2048;
  const size_t vbase = (size_t)prob * (64 * 2048);

  const float4_ z4 = (float4_){0.f, 0.f, 0.f, 0.f};
  short8 ones8;
#pragma unroll
  for (int zz = 0; zz < 8; zz++) ones8[zz] = (short)0x3F80;   // bf16 1.0

  // Q as B-operand frags (16x16x32): B[n=q=lrow][k=d=quad*8+j]
  short8 bq[2][2];
#pragma unroll
  for (int i = 0; i < 2; i++) {
    const unsigned short* qp = qg + (size_t)(mbase + q0 + w * 32 + i * 16 + lrow) * KDIM + h * 64 + quad * 8;
    bq[i][0] = *(const short8*)qp;
    bq[i][1] = *(const short8*)(qp + 32);
  }
  float4_ la[2];   // l accumulators via ones-MFMA: la[i][*] = l[q=i*16+lrow] (rows identical)
  float4_ oa[2][4];   // O^T tiles [i][dt]: row d = dt*16+quad*4+r, col q = i*16+lrow
#pragma unroll
  for (int i = 0; i < 2; i++) {
    la[i] = (float4_){0.f, 0.f, 0.f, 0.f};
#pragma unroll
    for (int d = 0; d < 4; d++) oa[i][d] = (float4_){0.f, 0.f, 0.f, 0.f};
  }

  auto stage = [&](int k0, int b) {
#pragma unroll
    for (int i2 = 0; i2 < 2; i2++) {
      const int li = i2 * 256 + t;
      const int row = li >> 3, p = li & 7;
      const int c = p ^ (row & 7);
      gll16(kg + (size_t)(mbase + k0 + row) * KDIM + h * 64 + c * 8, &Ks[b][li * 8]);
    }
#pragma unroll
    for (int i2 = 0; i2 < 2; i2++) {
      const int li = i2 * 256 + t;
      const int row = li >> 3, p = li & 7;
      const int c = p ^ (row & 7);
      gll16(vt + vbase + (size_t)row * 2048 + k0 + c * 8, &Vs[b][li * 8]);
    }
  };

  auto compute = [&](int b) {
    // S^T = K * Q^T (log2-scaled via Q), kk-outer; kk=0 takes z4 as C-in
    float4_ st[4][2];
    __builtin_amdgcn_s_setprio(1);
#pragma unroll
    for (int nt = 0; nt < 4; nt++) {
      short8 ak = *(const short8*)(&Ks[b][(nt * 16 + lrow) * 64 + ((quad ^ (lrow & 7)) * 8)]);
      st[nt][0] = __builtin_amdgcn_mfma_f32_16x16x32_bf16(ak, bq[0][0], z4, 0, 0, 0);
      st[nt][1] = __builtin_amdgcn_mfma_f32_16x16x32_bf16(ak, bq[1][0], z4, 0, 0, 0);
    }
#pragma unroll
    for (int nt = 0; nt < 4; nt++) {
      short8 ak = *(const short8*)(&Ks[b][(nt * 16 + lrow) * 64 + (((4 + quad) ^ (lrow & 7)) * 8)]);
      st[nt][0] = __builtin_amdgcn_mfma_f32_16x16x32_bf16(ak, bq[0][1], st[nt][0], 0, 0, 0);
      st[nt][1] = __builtin_amdgcn_mfma_f32_16x16x32_bf16(ak, bq[1][1], st[nt][1], 0, 0, 0);
    }
    __builtin_amdgcn_s_setprio(0);

    // exp2 (no max-sub; |logit|<~8), truncate-pack pairs -> PV B-frags in registers
    short4_ pb[2][4];
#pragma unroll
    for (int nt = 0; nt < 4; nt++)
#pragma unroll
      for (int i = 0; i < 2; i++) {
        const float p0 = __builtin_amdgcn_exp2f(st[nt][i][0]);
        const float p1 = __builtin_amdgcn_exp2f(st[nt][i][1]);
        const float p2 = __builtin_amdgcn_exp2f(st[nt][i][2]);
        const float p3 = __builtin_amdgcn_exp2f(st[nt][i][3]);
        uint2_ uu = { pack2bf_t(p0, p1), pack2bf_t(p2, p3) };
        pb[i][nt] = __builtin_bit_cast(short4_, uu);
      }

    // O^T += V^T * P and l += 1^T * P : 16x16x32, st tile pairs (2g,2g+1) fused along K
    __builtin_amdgcn_s_setprio(1);
#pragma unroll
    for (int g = 0; g < 2; g++) {
      const short8 b80 = __builtin_shufflevector(pb[0][2 * g], pb[0][2 * g + 1], 0, 1, 2, 3, 4, 5, 6, 7);
      const short8 b81 = __builtin_shufflevector(pb[1][2 * g], pb[1][2 * g + 1], 0, 1, 2, 3, 4, 5, 6, 7);
      la[0] = __builtin_amdgcn_mfma_f32_16x16x32_bf16(ones8, b80, la[0], 0, 0, 0);
      la[1] = __builtin_amdgcn_mfma_f32_16x16x32_bf16(ones8, b81, la[1], 0, 0, 0);
#pragma unroll
      for (int dt = 0; dt < 4; dt++) {
        const int rb = (dt * 16 + lrow) * 64 + (((g * 4 + quad) ^ (lrow & 7)) * 8);
        short8 a8 = *(const short8*)(&Vs[b][rb]);
        oa[0][dt] = __builtin_amdgcn_mfma_f32_16x16x32_bf16(a8, b80, oa[0][dt], 0, 0, 0);
        oa[1][dt] = __builtin_amdgcn_mfma_f32_16x16x32_bf16(a8, b81, oa[1][dt], 0, 0, 0);
      }
    }
    __builtin_amdgcn_s_setprio(0);
  };

  stage(0, 0);
  stage(64, 1);

#define STEP(KT, CUR, STG)                                   \
  do {                                                       \
    asm volatile("s_waitcnt vmcnt(4)" ::: "memory");         \
    __builtin_amdgcn_s_barrier();                            \
    __builtin_amdgcn_sched_barrier(0);                       \
    stage(((KT) + 2) * 64, (STG));                           \
    compute(CUR);                                            \
  } while (0)

  for (int kt0 = 0; kt0 < 30; kt0 += 3) {
    STEP(kt0, 0, 2);
    STEP(kt0 + 1, 1, 0);
    STEP(kt0 + 2, 2, 1);
  }
  // kt = 30 (buf 0): stage(31) still in flight
  asm volatile("s_waitcnt vmcnt(4)" ::: "memory");
  __builtin_amdgcn_s_barrier();
  __builtin_amdgcn_sched_barrier(0);
  compute(0);
  // kt = 31 (buf 1): drain
  asm volatile("s_waitcnt vmcnt(0)" ::: "memory");
  __builtin_amdgcn_s_barrier();
  __builtin_amdgcn_sched_barrier(0);
  compute(1);
#undef STEP

  // epilogue: l already reduced per-lane by ones-MFMA; normalize, packed 8B stores
#pragma unroll
  for (int i = 0; i < 2; i++) {
    const float inv = 1.0f / la[i][0];
    const size_t m = (size_t)mbase + q0 + w * 32 + i * 16 + lrow;
#pragma unroll
    for (int dt = 0; dt < 4; dt++) {
      uint2_ uu = { pack2bf(oa[i][dt][0] * inv, oa[i][dt][1] * inv),
                    pack2bf(oa[i][dt][2] * inv, oa[i][dt][3] * inv) };
      *(uint2_*)(o + m * KDIM + h * 64 + dt * 16 + quad * 4) = uu;
    }
  }
}

// ---------------- launch ----------------
extern "C" void kernel_launch(void* const* d_in, const int* in_sizes, int n_in,
                              void* d_out, int out_size, void* d_ws, size_t ws_size,
                              hipStream_t stream) {
  const float* x1 = (const float*)d_in[0];
  const float* x2 = (const float*)d_in[1];
  const float* Wq = (const float*)d_in[2];
  const float* bq = (const float*)d_in[3];
  const float* Wk = (const float*)d_in[4];
  const float* bk = (const float*)d_in[5];
  const float* Wv = (const float*)d_in[6];
  const float* bv = (const float*)d_in[7];
  const float* Wo = (const float*)d_in[8];
  const float* bo = (const float*)d_in[9];
  const float* cs = (const float*)d_in[10];
  float* out = (float*)d_out;

  char* ws = (char*)d_ws;
  size_t off = 0;
  auto alloc = [&](size_t bytes) {
    void* p = ws + off;
    off += (bytes + 255) & ~(size_t)255;
    return p;
  };
  unsigned short* xa  = (unsigned short*)alloc((size_t)XAELEMS * 2);
  unsigned short* xb  = (unsigned short*)alloc((size_t)XAELEMS * 2);
  unsigned short* wqb = (unsigned short*)alloc((size_t)WELEMS * 2);
  unsigned short* wkb = (unsigned short*)alloc((size_t)WELEMS * 2);
  unsigned short* wvb = (unsigned short*)alloc((size_t)WELEMS * 2);
  unsigned short* wob = (unsigned short*)alloc((size_t)WELEMS * 2);
  unsigned short* qg  = (unsigned short*)alloc((size_t)XAELEMS * 2);
  unsigned short* kgb = (unsigned short*)alloc((size_t)XAELEMS * 2);
  unsigned short* vtb = (unsigned short*)alloc((size_t)XAELEMS * 2);
  unsigned short* ob  = (unsigned short*)alloc((size_t)XAELEMS * 2);

  prep_x_kernel<<<HALF / 1024, 256, 0, stream>>>(x1, x2, cs, xa, xb);
  conv_w4_kernel<<<dim3(WELEMS / 1024, 4), 256, 0, stream>>>(Wq, Wk, Wv, Wo, wqb, wkb, wvb, wob);
  qkv_gemm<<<dim3(64, 6, 3), 256, 0, stream>>>(xa, xb, wqb, wkb, wvb, bq, bk, bv, qg, kgb, vtb);
  attn_kernel<<<48 * 16, 256, 0, stream>>>(qg, kgb, vtb, ob);
  out_gemm<<<dim3(64, 6), 256, 0, stream>>>(ob, wob, bo, out);
}